// Round 1
// 397.809 us; speedup vs baseline: 1.0189x; 1.0189x over previous
//
#include <hip/hip_runtime.h>
#include <cstdint>
#include <cstddef>
#include <math.h>

#define N_NODES 40000
#define N_RELS  474
#define E0      100000
#define EN      30000
#define NE      130000
#define NB      8192
#define LRALPHA 0.2f

#define KP1 128
#define KP2 256
// Pcat cols: [0:200) Pt interleaved | [200:400) Ps interleaved | [400:600) entW | [600:604) dots | pad
#define LD1 608
// Qcat cols: [0:200) Qt | [200:400) Qs | 400 dqt | 401 dqs | pad
#define LD2 416
#define NPAD1 640
#define NPAD2 448

typedef __attribute__((ext_vector_type(8))) short short8;
typedef __attribute__((ext_vector_type(4))) float floatx4;

static __device__ __forceinline__ unsigned short f2bf(float f) {
    union { float f; uint32_t u; } v; v.f = f;
    uint32_t r = v.u + 0x7fff + ((v.u >> 16) & 1);
    return (unsigned short)(r >> 16);
}
static __device__ __forceinline__ float bf2f(unsigned short h) {
    union { uint32_t u; float f; } v; v.u = ((uint32_t)h) << 16;
    return v.f;
}
static __device__ __forceinline__ float bflo(uint32_t u) { return bf2f((unsigned short)(u & 0xffff)); }
static __device__ __forceinline__ float bfhi(uint32_t u) { return bf2f((unsigned short)(u >> 16)); }

static __device__ __forceinline__ int rdl(int v, int l) {
    return __builtin_amdgcn_readlane(v, l);
}
static __device__ __forceinline__ float rdlf(float v, int l) {
    return __int_as_float(__builtin_amdgcn_readlane(__float_as_int(v), l));
}

// ---------------- l2norm rows of ent -> bf16 padded [40000][KP1] ----------------
__global__ void k_l2norm_bf16(const float* __restrict__ in, unsigned short* __restrict__ out) {
    int w = (blockIdx.x * blockDim.x + threadIdx.x) >> 6;
    int lane = threadIdx.x & 63;
    if (w >= N_NODES) return;
    const float* r = in + (size_t)w * 100;
    float v0 = r[lane];
    int j1 = lane + 64;
    float v1 = (j1 < 100) ? r[j1] : 0.f;
    float ss = v0 * v0 + v1 * v1;
#pragma unroll
    for (int o = 32; o > 0; o >>= 1) ss += __shfl_down(ss, o);
    ss = __shfl(ss, 0);
    float inv = 1.f / fmaxf(sqrtf(ss), 1e-12f);
    unsigned short* dst = out + (size_t)w * KP1;
    dst[lane] = f2bf(v0 * inv);
    dst[j1] = (j1 < 100) ? f2bf(v1 * inv) : (unsigned short)0;
}

// ---------------- bf16 MFMA GEMM: fragment-ordered B (coalesced), 4-way ILP ----------------
template <int KP>
__global__ __launch_bounds__(256) void k_gemm_mfma(const unsigned short* __restrict__ A,
                                                   const unsigned short* __restrict__ B,
                                                   unsigned short* __restrict__ C,
                                                   int ldc, int N, int gPerSplit) {
    constexpr int KSTEPS = KP / 32;
    constexpr int KCH = KSTEPS / 4;
    __shared__ unsigned short cbuf[4][16][64];
    int wave = threadIdx.x >> 6;
    int lane = threadIdx.x & 63;
    int quad = lane >> 4;
    int l16 = lane & 15;
    int m0 = blockIdx.x * 64 + wave * 16;
    short8 afrag[KSTEPS];
    const unsigned short* arow = A + (size_t)(m0 + l16) * KP + quad * 8;
#pragma unroll
    for (int ks = 0; ks < KSTEPS; ks++)
        afrag[ks] = *(const short8*)(arow + ks * 32);

    int Gtot = (N + 63) >> 6;
    int g0 = blockIdx.y * gPerSplit;
    int g1 = g0 + gPerSplit;
    if (g1 > Gtot) g1 = Gtot;
    for (int g = g0; g < g1; g++) {
        int nb = g << 6;
        const unsigned short* bgrp = B + (((size_t)(g << 2) * KSTEPS) << 9) + (lane << 3);
        floatx4 acc[4];
#pragma unroll
        for (int t = 0; t < 4; t++) acc[t] = (floatx4){0.f, 0.f, 0.f, 0.f};
#pragma unroll
        for (int ch = 0; ch < KCH; ch++) {
            short8 bf[4][4];
#pragma unroll
            for (int t = 0; t < 4; t++)
#pragma unroll
                for (int k = 0; k < 4; k++)
                    bf[t][k] = *(const short8*)(bgrp + ((size_t)(t * KSTEPS + ch * 4 + k) << 9));
#pragma unroll
            for (int k = 0; k < 4; k++)
#pragma unroll
                for (int t = 0; t < 4; t++)
                    acc[t] = __builtin_amdgcn_mfma_f32_16x16x32_bf16(afrag[ch * 4 + k], bf[t][k], acc[t], 0, 0, 0);
        }
        int r0 = quad * 4;
#pragma unroll
        for (int t = 0; t < 4; t++)
#pragma unroll
            for (int i = 0; i < 4; i++)
                cbuf[wave][r0 + i][t * 16 + l16] = f2bf(acc[t][i]);
        int colsA = N - nb; if (colsA > 64) colsA = 64;
        int cols8 = colsA >> 3;
        int sh = (colsA >= 64) ? 3 : 2;
        int nchunks = cols8 << 4;
        for (int c = lane; c < nchunks; c += 64) {
            int row = c >> sh;
            int col8 = (c & (cols8 - 1)) << 3;
            *(uint4*)(C + (size_t)(m0 + row) * ldc + nb + col8) =
                *(const uint4*)&cbuf[wave][row][col8];
        }
    }
}

// ---------------- u-vectors ----------------
__global__ void k_uvec(const float* __restrict__ att_a, const float* __restrict__ att_a2,
                       const float* __restrict__ out_a, const float* __restrict__ out_a2,
                       float* __restrict__ uvecs) {
    int tid = blockIdx.x * blockDim.x + threadIdx.x;
    if (tid >= 800) return;
    float s = 0.f;
    if (tid < 400) {
        int v = tid / 100, k = tid % 100;
        int head = v >> 1, part = v & 1;
        const float* base = att_a + head * 30000 + part * 100 + k;
        const float* a2 = att_a2 + head * 100;
        for (int n = 0; n < 100; n++) s += a2[n] * base[n * 300];
        uvecs[tid] = s;
    } else {
        int v = (tid - 400) / 200, k = (tid - 400) % 200;
        const float* base = out_a + v * 200 + k;
        for (int n = 0; n < 200; n++) s += out_a2[n] * base[n * 600];
        uvecs[400 + v * 200 + k] = s;
    }
}

// ---------------- pack layer-1 B matrix -> FRAGMENT ORDER ----------------
__global__ void k_pack1(const float* __restrict__ att_a, const float* __restrict__ W_ent,
                        const float* __restrict__ uvecs, unsigned short* __restrict__ W) {
    int idx = blockIdx.x * blockDim.x + threadIdx.x;
    if (idx >= NPAD1 * KP1) return;
    int j = idx & 7;
    int lane = (idx >> 3) & 63;
    int u = idx >> 9;
    int ks = u & 3;
    int t = u >> 2;
    int r = t * 16 + (lane & 15);
    int k = ks * 32 + (lane >> 4) * 8 + j;
    float val = 0.f;
    if (k < 100) {
        if (r < 200) {
            int i = r >> 1, h = r & 1;
            val = att_a[h * 30000 + i * 300 + k];
        } else if (r < 400) {
            int rr = r - 200, i = rr >> 1, h = rr & 1;
            val = att_a[h * 30000 + i * 300 + 100 + k];
        } else if (r < 600) {
            val = W_ent[k * 200 + (r - 400)];
        } else if (r < 604) {
            val = uvecs[(r - 600) * 100 + k];
        }
    }
    W[idx] = f2bf(val);
}

// ---------------- pack layer-2 B matrix -> FRAGMENT ORDER ----------------
__global__ void k_pack2(const float* __restrict__ out_a, const float* __restrict__ uvecs,
                        unsigned short* __restrict__ W) {
    int idx = blockIdx.x * blockDim.x + threadIdx.x;
    if (idx >= NPAD2 * KP2) return;
    int j = idx & 7;
    int lane = (idx >> 3) & 63;
    int u = idx >> 9;
    int ks = u & 7;
    int t = u >> 3;
    int r = t * 16 + (lane & 15);
    int k = ks * 32 + (lane >> 4) * 8 + j;
    float val = 0.f;
    if (k < 200) {
        int klog = (k & 1) * 100 + (k >> 1);
        if (r < 200)       val = out_a[r * 600 + klog];
        else if (r < 400)  val = out_a[(r - 200) * 600 + 200 + klog];
        else if (r == 400) val = uvecs[400 + klog];
        else if (r == 401) val = uvecs[600 + klog];
    }
    W[idx] = f2bf(val);
}

// ---------------- R1 interleaved projection ----------------
__global__ void k_relproj1(const float* __restrict__ rel_emb, const float* __restrict__ att_a,
                           float* __restrict__ R1i) {
    int w = (blockIdx.x * blockDim.x + threadIdx.x) >> 6;
    int lane = threadIdx.x & 63;
    if (w >= N_RELS) return;
    const float* re = rel_emb + (size_t)w * 100;
    float2* dst = (float2*)(R1i + (size_t)w * 200);
    for (int f = lane; f < 100; f += 64) {
        const float* a0 = att_a + f * 300 + 200;
        const float* a1 = att_a + 30000 + f * 300 + 200;
        float s0 = 0.f, s1 = 0.f;
        for (int k = 0; k < 100; k++) {
            float rk = re[k];
            s0 += rk * a0[k];
            s1 += rk * a1[k];
        }
        dst[f] = make_float2(s0, s1);
    }
}

__global__ void k_dR1(const float* __restrict__ R1i, const float* __restrict__ att_a2,
                      float* __restrict__ dR10, float* __restrict__ dR11) {
    int w = (blockIdx.x * blockDim.x + threadIdx.x) >> 6;
    int lane = threadIdx.x & 63;
    if (w >= N_RELS) return;
    const float2* row = (const float2*)(R1i + (size_t)w * 200);
    float s0 = 0.f, s1 = 0.f;
    for (int f = lane; f < 100; f += 64) {
        float2 v = row[f];
        s0 += v.x * att_a2[f];
        s1 += v.y * att_a2[100 + f];
    }
#pragma unroll
    for (int o = 32; o > 0; o >>= 1) {
        s0 += __shfl_down(s0, o);
        s1 += __shfl_down(s1, o);
    }
    if (lane == 0) { dR10[w] = s0; dR11[w] = s1; }
}

// ---------------- generic tiled fp32 matmul (474-row cases only) ----------------
template <bool BT>
__global__ __launch_bounds__(256) void k_mm(const float* __restrict__ A, int lda,
                                            const float* __restrict__ B, int ldb,
                                            float* __restrict__ C, int ldc,
                                            int M, int N, int K) {
    __shared__ float As[16][65];
    __shared__ float Bs[16][65];
    int tid = threadIdx.x;
    int tx = tid & 15, ty = tid >> 4;
    int m0 = blockIdx.y * 64, n0 = blockIdx.x * 64;
    float acc[4][4] = {};
    for (int k0 = 0; k0 < K; k0 += 16) {
        {
            int r = tid >> 2;
            int c4 = (tid & 3) * 4;
            int m = m0 + r;
#pragma unroll
            for (int u = 0; u < 4; u++) {
                int k = k0 + c4 + u;
                As[c4 + u][r] = (m < M && k < K) ? A[(size_t)m * lda + k] : 0.f;
            }
        }
        if (BT) {
            int r = tid >> 2;
            int c4 = (tid & 3) * 4;
            int n = n0 + r;
#pragma unroll
            for (int u = 0; u < 4; u++) {
                int k = k0 + c4 + u;
                Bs[c4 + u][r] = (n < N && k < K) ? B[(size_t)n * ldb + k] : 0.f;
            }
        } else {
            int kk = tid >> 4;
            int nn4 = (tid & 15) * 4;
            int k = k0 + kk;
#pragma unroll
            for (int u = 0; u < 4; u++) {
                int n = n0 + nn4 + u;
                Bs[kk][nn4 + u] = (k < K && n < N) ? B[(size_t)k * ldb + n] : 0.f;
            }
        }
        __syncthreads();
#pragma unroll
        for (int k = 0; k < 16; k++) {
            float a[4], b[4];
#pragma unroll
            for (int i = 0; i < 4; i++) a[i] = As[k][ty + 16 * i];
#pragma unroll
            for (int j = 0; j < 4; j++) b[j] = Bs[k][tx + 16 * j];
#pragma unroll
            for (int i = 0; i < 4; i++)
#pragma unroll
                for (int j = 0; j < 4; j++) acc[i][j] += a[i] * b[j];
        }
        __syncthreads();
    }
#pragma unroll
    for (int i = 0; i < 4; i++) {
        int m = m0 + ty + 16 * i;
        if (m >= M) continue;
#pragma unroll
        for (int j = 0; j < 4; j++) {
            int n = n0 + tx + 16 * j;
            if (n < N) C[(size_t)m * ldc + n] = acc[i][j];
        }
    }
}

// ---------------- per-row dot with vector ----------------
__global__ void k_dotv(const float* __restrict__ mat, const float* __restrict__ vec,
                       float* __restrict__ out, int M, int F) {
    int w = (blockIdx.x * blockDim.x + threadIdx.x) >> 6;
    int lane = threadIdx.x & 63;
    if (w >= M) return;
    const float* r = mat + (size_t)w * F;
    float s = 0.f;
    for (int j = lane; j < F; j += 64) s += r[j] * vec[j];
#pragma unroll
    for (int o = 32; o > 0; o >>= 1) s += __shfl_down(s, o);
    if (lane == 0) out[w] = s;
}

// ---------------- CSR build ----------------
__global__ void k_hist(const int* __restrict__ tgt_el, const int* __restrict__ nhop,
                       int* __restrict__ deg) {
    int e = blockIdx.x * blockDim.x + threadIdx.x;
    if (e >= NE) return;
    int t = (e < E0) ? tgt_el[e] : nhop[(size_t)(e - E0) * 4 + 3];
    atomicAdd(&deg[t], 1);
}

__global__ void k_scan1(const int* __restrict__ deg, int* __restrict__ local,
                        int* __restrict__ bsums, int n) {
    int i = blockIdx.x * 256 + threadIdx.x;
    int v = (i < n) ? deg[i] : 0;
    int lane = threadIdx.x & 63;
    int wv = threadIdx.x >> 6;
    int x = v;
#pragma unroll
    for (int o = 1; o < 64; o <<= 1) {
        int t = __shfl_up(x, o);
        if (lane >= o) x += t;
    }
    __shared__ int wtot[4];
    if (lane == 63) wtot[wv] = x;
    __syncthreads();
    int add = 0;
    for (int k = 0; k < wv; k++) add += wtot[k];
    if (i < n) local[i] = add + x - v;
    if (threadIdx.x == 255) bsums[blockIdx.x] = add + x;
}

__global__ void k_scan2(int* __restrict__ bsums, int nb) {
    int tid = threadIdx.x;
    int v = (tid < nb) ? bsums[tid] : 0;
    int lane = tid & 63, wv = tid >> 6;
    int x = v;
#pragma unroll
    for (int o = 1; o < 64; o <<= 1) {
        int t = __shfl_up(x, o);
        if (lane >= o) x += t;
    }
    __shared__ int wtot[4];
    if (lane == 63) wtot[wv] = x;
    __syncthreads();
    int add = 0;
    for (int k = 0; k < wv; k++) add += wtot[k];
    __syncthreads();
    if (tid < nb) bsums[tid] = add + x - v;
    if (tid == 255) bsums[nb] = add + x;
}

__global__ void k_scan3(const int* __restrict__ local, const int* __restrict__ bsums,
                        int* __restrict__ rowptr, int* __restrict__ cursor, int n, int nb) {
    int i = blockIdx.x * 256 + threadIdx.x;
    if (i < n) {
        int v = local[i] + bsums[blockIdx.x];
        rowptr[i] = v;
        cursor[i] = v;
    } else if (i == n) {
        rowptr[n] = bsums[nb];
    }
}

__global__ void k_scatter(const int* __restrict__ tgt_el, const int* __restrict__ src_el,
                          const int* __restrict__ etype, const int* __restrict__ nhop,
                          int* __restrict__ cursor,
                          int* __restrict__ srcs, int2* __restrict__ relpk) {
    int e = blockIdx.x * blockDim.x + threadIdx.x;
    if (e >= NE) return;
    int t, s, r1, r2;
    if (e < E0) {
        t = tgt_el[e]; s = src_el[e]; r1 = etype[e]; r2 = -1;
    } else {
        const int* nh = nhop + (size_t)(e - E0) * 4;
        t = nh[3]; s = nh[0]; r1 = nh[1]; r2 = nh[2];
    }
    int p = atomicAdd(&cursor[t], 1);
    srcs[p] = s;
    relpk[p] = make_int2(r1, r2);
}

// ---------------- node aggregation layer 1 (fused edge weights) ----------------
// lane l < 50 handles interleaved cols [4l, 4l+4); metadata broadcast via readlane (SGPR addressing)
__global__ __launch_bounds__(256, 4) void k_node1(
                        const int* __restrict__ rowptr, const int* __restrict__ srcs,
                        const int2* __restrict__ relpk,
                        const unsigned short* __restrict__ Pcat,
                        const float* __restrict__ R1i,
                        const float* __restrict__ dR10, const float* __restrict__ dR11,
                        unsigned short* __restrict__ x) {
    int node = (blockIdx.x * blockDim.x + threadIdx.x) >> 6;
    node = __builtin_amdgcn_readfirstlane(node);
    int lane = threadIdx.x & 63;
    if (node >= N_NODES) return;
    bool fv = (lane < 50);
    int c4 = lane * 4;                       // interleaved col offset
    int beg = rowptr[node], end = rowptr[node + 1];
    int deg = end - beg;
    int fast = (deg < 64) ? deg : 64;
    // per-node target dots (uniform)
    uint2 td = *(const uint2*)(Pcat + (size_t)node * LD1 + 600);
    float t0h = bflo(td.x), t1h = bflo(td.y);
    // lane-parallel metadata + inline edge-weight computation (was k_edge1)
    int sL = 0, rxL = 0, ryL = -1;
    float wxL = 0.f, wyL = 0.f;
    if (lane < fast) {
        int p = beg + lane;
        sL = srcs[p];
        int2 rp = relpk[p];
        rxL = rp.x; ryL = rp.y;
        float dr0 = dR10[rp.x], dr1 = dR11[rp.x];
        if (rp.y >= 0) { dr0 += dR10[rp.y]; dr1 += dR11[rp.y]; }
        uint2 sd = *(const uint2*)(Pcat + (size_t)sL * LD1 + 600);
        float p0 = t0h + bfhi(sd.x) + dr0;
        float p1 = t1h + bfhi(sd.y) + dr1;
        p0 = (p0 >= 0.f) ? p0 : LRALPHA * p0;
        p1 = (p1 >= 0.f) ? p1 : LRALPHA * p1;
        wxL = expf(-p0);
        wyL = expf(-p1);
    }
    float b0 = 0.f, b1 = 0.f, b2 = 0.f, b3 = 0.f;   // (2l,h0) (2l,h1) (2l+1,h0) (2l+1,h1)
    float rs0 = 0.f, rs1 = 0.f;
    for (int j = 0; j < fast; j += 4) {
#pragma unroll
        for (int u = 0; u < 4; u++) {
            int jj = j + u;
            bool act = (jj < fast);
            int ls = act ? jj : 0;
            int sE = rdl(sL, ls);
            int rxE = rdl(rxL, ls);
            int ryE = act ? rdl(ryL, ls) : -1;
            float wxE = act ? rdlf(wxL, ls) : 0.f;
            float wyE = act ? rdlf(wyL, ls) : 0.f;
            uint2 ps = make_uint2(0u, 0u);
            float4 rv = make_float4(0.f, 0.f, 0.f, 0.f);
            if (fv) {
                ps = *(const uint2*)(Pcat + (size_t)sE * LD1 + 200 + c4);
                rv = *(const float4*)(R1i + (size_t)rxE * 200 + c4);
                if (ryE >= 0) {
                    float4 rb = *(const float4*)(R1i + (size_t)ryE * 200 + c4);
                    rv.x += rb.x; rv.y += rb.y; rv.z += rb.z; rv.w += rb.w;
                }
            }
            rs0 += wxE; rs1 += wyE;
            b0 += wxE * (bflo(ps.x) + rv.x);
            b1 += wyE * (bfhi(ps.x) + rv.y);
            b2 += wxE * (bflo(ps.y) + rv.z);
            b3 += wyE * (bfhi(ps.y) + rv.w);
        }
    }
    // rare deg>64 tail (uniform per-edge loads)
    for (int p = beg + 64; p < end; p++) {
        int sE = srcs[p];
        int2 rp = relpk[p];
        float dr0 = dR10[rp.x], dr1 = dR11[rp.x];
        if (rp.y >= 0) { dr0 += dR10[rp.y]; dr1 += dR11[rp.y]; }
        uint2 sd = *(const uint2*)(Pcat + (size_t)sE * LD1 + 600);
        float p0 = t0h + bfhi(sd.x) + dr0;
        float p1 = t1h + bfhi(sd.y) + dr1;
        p0 = (p0 >= 0.f) ? p0 : LRALPHA * p0;
        p1 = (p1 >= 0.f) ? p1 : LRALPHA * p1;
        float wx = expf(-p0), wy = expf(-p1);
        uint2 ps = make_uint2(0u, 0u);
        float4 rv = make_float4(0.f, 0.f, 0.f, 0.f);
        if (fv) {
            ps = *(const uint2*)(Pcat + (size_t)sE * LD1 + 200 + c4);
            rv = *(const float4*)(R1i + (size_t)rp.x * 200 + c4);
            if (rp.y >= 0) {
                float4 rb = *(const float4*)(R1i + (size_t)rp.y * 200 + c4);
                rv.x += rb.x; rv.y += rb.y; rv.z += rb.z; rv.w += rb.w;
            }
        }
        rs0 += wx; rs1 += wy;
        b0 += wx * (bflo(ps.x) + rv.x);
        b1 += wy * (bfhi(ps.x) + rv.y);
        b2 += wx * (bflo(ps.y) + rv.z);
        b3 += wy * (bfhi(ps.y) + rv.w);
    }
    float d0 = (rs0 == 0.f) ? 1e-12f : rs0;
    float d1 = (rs1 == 0.f) ? 1e-12f : rs1;
    unsigned short* xr = x + (size_t)node * KP2;
    if (fv) {
        uint2 pt = *(const uint2*)(Pcat + (size_t)node * LD1 + c4);
        float v0 = (b0 + rs0 * bflo(pt.x)) / d0;
        float v1 = (b1 + rs1 * bfhi(pt.x)) / d1;
        float v2 = (b2 + rs0 * bflo(pt.y)) / d0;
        float v3 = (b3 + rs1 * bfhi(pt.y)) / d1;
        v0 = (v0 > 0.f) ? v0 : expm1f(v0);
        v1 = (v1 > 0.f) ? v1 : expm1f(v1);
        v2 = (v2 > 0.f) ? v2 : expm1f(v2);
        v3 = (v3 > 0.f) ? v3 : expm1f(v3);
        uint2 w;
        w.x = (uint32_t)f2bf(v0) | ((uint32_t)f2bf(v1) << 16);
        w.y = (uint32_t)f2bf(v2) | ((uint32_t)f2bf(v3) << 16);
        *(uint2*)(xr + c4) = w;
    } else {
        // lanes 50..63 zero-fill padding cols [200,256)
        *(uint2*)(xr + 200 + (lane - 50) * 4) = make_uint2(0u, 0u);
    }
}

// ---------------- node aggregation layer 2 (fused edge weights + final fuse) ----------------
__global__ __launch_bounds__(256, 4) void k_node2(
                        const int* __restrict__ rowptr, const int* __restrict__ srcs,
                        const int2* __restrict__ relpk,
                        const unsigned short* __restrict__ Qcat,
                        const unsigned short* __restrict__ Pcat,
                        const float* __restrict__ R2, const float* __restrict__ dR2,
                        const float* __restrict__ mask,
                        float* __restrict__ out) {
    int node = (blockIdx.x * blockDim.x + threadIdx.x) >> 6;
    node = __builtin_amdgcn_readfirstlane(node);
    int lane = threadIdx.x & 63;
    if (node >= N_NODES) return;
    bool fv = (lane < 50);
    int c4 = lane * 4;
    int beg = rowptr[node], end = rowptr[node + 1];
    int deg = end - beg;
    int fast = (deg < 64) ? deg : 64;
    // per-node target dot (uniform)
    uint32_t tq = *(const uint32_t*)(Qcat + (size_t)node * LD2 + 400);
    float tdot = bflo(tq);
    // lane-parallel metadata + inline edge-weight computation (was k_edge2)
    int sL = 0, rxL = 0, ryL = -1;
    float WL = 0.f;
    if (lane < fast) {
        int p = beg + lane;
        sL = srcs[p];
        int2 rp = relpk[p];
        rxL = rp.x; ryL = rp.y;
        float dr = dR2[rp.x];
        if (rp.y >= 0) dr += dR2[rp.y];
        uint32_t sq = *(const uint32_t*)(Qcat + (size_t)sL * LD2 + 400);
        float pp = tdot + bfhi(sq) + dr;
        pp = (pp >= 0.f) ? pp : LRALPHA * pp;
        WL = expf(-pp);
    }
    float c0 = 0.f, c1 = 0.f, c2 = 0.f, c3 = 0.f;
    float rs = 0.f;
    for (int j = 0; j < fast; j += 4) {
#pragma unroll
        for (int u = 0; u < 4; u++) {
            int jj = j + u;
            bool act = (jj < fast);
            int ls = act ? jj : 0;
            int sE = rdl(sL, ls);
            int rxE = rdl(rxL, ls);
            int ryE = act ? rdl(ryL, ls) : -1;
            float WE = act ? rdlf(WL, ls) : 0.f;
            uint2 qv = make_uint2(0u, 0u);
            float4 rv = make_float4(0.f, 0.f, 0.f, 0.f);
            if (fv) {
                qv = *(const uint2*)(Qcat + (size_t)sE * LD2 + 200 + c4);
                rv = *(const float4*)(R2 + (size_t)rxE * 200 + c4);
                if (ryE >= 0) {
                    float4 rb = *(const float4*)(R2 + (size_t)ryE * 200 + c4);
                    rv.x += rb.x; rv.y += rb.y; rv.z += rb.z; rv.w += rb.w;
                }
            }
            rs += WE;
            c0 += WE * (bflo(qv.x) + rv.x);
            c1 += WE * (bfhi(qv.x) + rv.y);
            c2 += WE * (bflo(qv.y) + rv.z);
            c3 += WE * (bfhi(qv.y) + rv.w);
        }
    }
    // rare deg>64 tail
    for (int p = beg + 64; p < end; p++) {
        int sE = srcs[p];
        int2 rp = relpk[p];
        float dr = dR2[rp.x];
        if (rp.y >= 0) dr += dR2[rp.y];
        uint32_t sq = *(const uint32_t*)(Qcat + (size_t)sE * LD2 + 400);
        float pp = tdot + bfhi(sq) + dr;
        pp = (pp >= 0.f) ? pp : LRALPHA * pp;
        float W = expf(-pp);
        uint2 qv = make_uint2(0u, 0u);
        float4 rv = make_float4(0.f, 0.f, 0.f, 0.f);
        if (fv) {
            qv = *(const uint2*)(Qcat + (size_t)sE * LD2 + 200 + c4);
            rv = *(const float4*)(R2 + (size_t)rp.x * 200 + c4);
            if (rp.y >= 0) {
                float4 rb = *(const float4*)(R2 + (size_t)rp.y * 200 + c4);
                rv.x += rb.x; rv.y += rb.y; rv.z += rb.z; rv.w += rb.w;
            }
        }
        rs += W;
        c0 += W * (bflo(qv.x) + rv.x);
        c1 += W * (bfhi(qv.x) + rv.y);
        c2 += W * (bflo(qv.y) + rv.z);
        c3 += W * (bfhi(qv.y) + rv.w);
    }
    float d = (rs == 0.f) ? 1e-12f : rs;
    float mk = mask[node];
    float val0 = 0.f, val1 = 0.f, val2 = 0.f, val3 = 0.f;
    if (fv) {
        uint2 t = *(const uint2*)(Qcat + (size_t)node * LD2 + c4);
        uint2 e = *(const uint2*)(Pcat + (size_t)node * LD1 + 400 + c4);
        val0 = bflo(e.x) + mk * ((c0 + rs * bflo(t.x)) / d);
        val1 = bfhi(e.x) + mk * ((c1 + rs * bfhi(t.x)) / d);
        val2 = bflo(e.y) + mk * ((c2 + rs * bflo(t.y)) / d);
        val3 = bfhi(e.y) + mk * ((c3 + rs * bfhi(t.y)) / d);
    }
    float ss = val0 * val0 + val1 * val1 + val2 * val2 + val3 * val3;
#pragma unroll
    for (int o = 32; o > 0; o >>= 1) ss += __shfl_down(ss, o);
    ss = __shfl(ss, 0);
    float inv = 1.f / fmaxf(sqrtf(ss), 1e-12f);
    if (fv) {
        *(float4*)(out + (size_t)node * 200 + c4) =
            make_float4(val0 * inv, val1 * inv, val2 * inv, val3 * inv);
    }
}

// ---------------- mask scatter ----------------
__global__ void k_mask(const int* __restrict__ batch, float* __restrict__ mask) {
    int i = blockIdx.x * blockDim.x + threadIdx.x;
    if (i < NB) mask[batch[(size_t)i * 3 + 2]] = 1.0f;
}

// ---------------- ortho losses ----------------
__global__ void k_ortho_part(const float* __restrict__ att_a, const float* __restrict__ out_a,
                             float* __restrict__ accum) {
    float loc[9] = {0,0,0,0,0,0,0,0,0};
    int stride = gridDim.x * blockDim.x;
    for (int i = blockIdx.x * blockDim.x + threadIdx.x; i < 90000; i += stride) {
        int seg, li;
        const float* base;
        int L;
        if (i < 15000)      { seg = 0; li = i;          base = att_a;         L = 15000; }
        else if (i < 30000) { seg = 1; li = i - 15000;  base = att_a + 30000; L = 15000; }
        else                { seg = 2; li = i - 30000;  base = out_a;         L = 60000; }
        float a = base[li], b = base[L + li];
        loc[seg * 3 + 0] += a * a;
        loc[seg * 3 + 1] += b * b;
        loc[seg * 3 + 2] += a * b;
    }
    int lane = threadIdx.x & 63;
#pragma unroll
    for (int q = 0; q < 9; q++) {
        float s = loc[q];
#pragma unroll
        for (int o = 32; o > 0; o >>= 1) s += __shfl_down(s, o);
        if (lane == 0 && s != 0.f) atomicAdd(&accum[q], s);
    }
}

__global__ void k_ortho_fin(const float* __restrict__ accum, float* __restrict__ out_scalar) {
    if (threadIdx.x != 0 || blockIdx.x != 0) return;
    float total = 0.f;
#pragma unroll
    for (int m = 0; m < 3; m++) {
        float s0 = accum[m * 3 + 0], s1 = accum[m * 3 + 1], sc = accum[m * 3 + 2];
        float c = sc / (fmaxf(sqrtf(s0), 1e-12f) * fmaxf(sqrtf(s1), 1e-12f));
        total += 0.01f * 2.f * c * c;
    }
    out_scalar[0] = total;
}

// ---------------- launch ----------------
extern "C" void kernel_launch(void* const* d_in, const int* in_sizes, int n_in,
                              void* d_out, int out_size, void* d_ws, size_t ws_size,
                              hipStream_t stream) {
    const int* edge_list = (const int*)d_in[0];
    const int* edge_type = (const int*)d_in[1];
    const int* batch     = (const int*)d_in[2];
    const int* nhop      = (const int*)d_in[3];
    const float* ent_emb = (const float*)d_in[4];
    const float* rel_emb = (const float*)d_in[5];
    const float* W_ent   = (const float*)d_in[6];
    const float* W_rel   = (const float*)d_in[7];
    const float* att_a   = (const float*)d_in[8];
    const float* att_a2  = (const float*)d_in[9];
    const float* out_a   = (const float*)d_in[10];
    const float* out_a2  = (const float*)d_in[11];
    float* out = (float*)d_out;
    const int* tgt_el = edge_list;
    const int* src_el = edge_list + E0;

    char* ws = (char*)d_ws;
    size_t o = 0;
    auto alloc = [&](size_t nbytes) -> char* {
        char* p = ws + o;
        o += (nbytes + 255) & ~(size_t)255;
        return p;
    };
    unsigned short* ent_bf  = (unsigned short*)alloc((size_t)N_NODES * KP1 * 2);
    unsigned short* x_bf    = (unsigned short*)alloc((size_t)N_NODES * KP2 * 2);
    unsigned short* Pcat    = (unsigned short*)alloc((size_t)N_NODES * LD1 * 2);
    unsigned short* Qcat    = (unsigned short*)alloc((size_t)N_NODES * LD2 * 2);
    unsigned short* Wcat1   = (unsigned short*)alloc((size_t)NPAD1 * KP1 * 2);
    unsigned short* Wcat2   = (unsigned short*)alloc((size_t)NPAD2 * KP2 * 2);
    float* uvecs = (float*)alloc(800 * 4);
    float* R1i   = (float*)alloc(474u * 200 * 4);
    float* R2    = (float*)alloc(474u * 200 * 4);
    float* dR10  = (float*)alloc(474u * 4);
    float* dR11  = (float*)alloc(474u * 4);
    float* dR2   = (float*)alloc(474u * 4);
    int* rowptr  = (int*)alloc((N_NODES + 1) * 4);
    int* cursor  = (int*)alloc(N_NODES * 4);
    int* srcs    = (int*)alloc((size_t)NE * 4);
    int2* relpk  = (int2*)alloc((size_t)NE * 8);
    float* mask  = (float*)alloc(N_NODES * 4);
    int* scanloc = (int*)alloc(N_NODES * 4);
    int* bsums   = (int*)alloc(260 * 4);
    float* oacc  = (float*)alloc(9 * 4);

    const int TPB = 256;
    int wave_blocks_40000 = (N_NODES * 64 + TPB - 1) / TPB;   // 10000
    int wave_blocks_474   = (N_RELS * 64 + TPB - 1) / TPB;    // 119
    int edge_blocks       = (NE + TPB - 1) / TPB;
    int scan_blocks       = (N_NODES + 255) / 256;            // 157

    hipMemsetAsync(cursor, 0, N_NODES * 4, stream);
    hipMemsetAsync(mask, 0, N_NODES * 4, stream);
    hipMemsetAsync(oacc, 0, 9 * 4, stream);

    // 1) normalize entities -> bf16 padded
    k_l2norm_bf16<<<wave_blocks_40000, TPB, 0, stream>>>(ent_emb, ent_bf);

    // 2) CSR by target, payloads in CSR order
    k_hist<<<edge_blocks, TPB, 0, stream>>>(tgt_el, nhop, cursor);
    k_scan1<<<scan_blocks, 256, 0, stream>>>(cursor, scanloc, bsums, N_NODES);
    k_scan2<<<1, 256, 0, stream>>>(bsums, scan_blocks);
    k_scan3<<<(N_NODES + 1 + 255) / 256, 256, 0, stream>>>(scanloc, bsums, rowptr, cursor, N_NODES, scan_blocks);
    k_scatter<<<edge_blocks, TPB, 0, stream>>>(tgt_el, src_el, edge_type, nhop, cursor,
                                               srcs, relpk);

    // 3) pack fused B matrices (fragment order)
    k_uvec<<<4, 256, 0, stream>>>(att_a, att_a2, out_a, out_a2, uvecs);
    k_pack1<<<(NPAD1 * KP1 + 255) / 256, 256, 0, stream>>>(att_a, W_ent, uvecs, Wcat1);
    k_pack2<<<(NPAD2 * KP2 + 255) / 256, 256, 0, stream>>>(out_a, uvecs, Wcat2);

    // 4) fused layer-1 GEMM
    k_gemm_mfma<KP1><<<dim3(625, 2), 256, 0, stream>>>(ent_bf, Wcat1, Pcat, LD1, 608, 5);

    // 5) relation-side projections + dots
    k_relproj1<<<wave_blocks_474, TPB, 0, stream>>>(rel_emb, att_a, R1i);
    k_dR1<<<wave_blocks_474, TPB, 0, stream>>>(R1i, att_a2, dR10, dR11);

    // 6) layer-1 aggregation (edge weights fused in) -> x_bf
    k_node1<<<wave_blocks_40000, TPB, 0, stream>>>(rowptr, srcs, relpk, Pcat, R1i, dR10, dR11, x_bf);

    // 7) fused layer-2 GEMM
    k_gemm_mfma<KP2><<<dim3(625, 2), 256, 0, stream>>>(x_bf, Wcat2, Qcat, LD2, 416, 4);

    // 8) out_relation_1; R2; dR2
    dim3 gor((200 + 63) / 64, (N_RELS + 63) / 64);
    k_mm<false><<<gor, TPB, 0, stream>>>(rel_emb, 100, W_rel, 200, out + 8000000, 200, N_RELS, 200, 100);
    k_mm<true><<<gor, TPB, 0, stream>>>(out + 8000000, 200, out_a + 400, 600, R2, 200, N_RELS, 200, 200);
    k_dotv<<<wave_blocks_474, TPB, 0, stream>>>(R2, out_a2, dR2, N_RELS, 200);

    // 9) mask, layer-2 aggregation (edge weights fused in) + final fuse
    k_mask<<<(NB + TPB - 1) / TPB, TPB, 0, stream>>>(batch, mask);
    k_node2<<<wave_blocks_40000, TPB, 0, stream>>>(rowptr, srcs, relpk, Qcat, Pcat, R2, dR2, mask, out);

    // 10) ortho scalar
    k_ortho_part<<<128, 256, 0, stream>>>(att_a, out_a, oacc);
    k_ortho_fin<<<1, 64, 0, stream>>>(oacc, out + 8094800);
}